// Round 1
// baseline (323.340 us; speedup 1.0000x reference)
//
#include <hip/hip_runtime.h>

// Problem constants
constexpr int Bn = 32, Tn = 8, Cn = 1024, Sn = 4096, Hn = 16, HDn = 64;
constexpr int NCHUNK = 16;      // 4096 / 256 keys per chunk-block
constexpr int KSPLIT = 4;       // K-split for the 256x1024x1024 GEMMs
constexpr float SCALE = 0.125f; // 1/sqrt(64)

// Workspace layout (in floats)
constexpr size_t PROJ_PART = (size_t)Bn * Tn * Cn;          // 262144 (one partial)
constexpr size_t QP_OFF = 0;
constexpr size_t KP_OFF = QP_OFF + KSPLIT * PROJ_PART;      // 1048576
constexpr size_t VP_OFF = KP_OFF + KSPLIT * PROJ_PART;
constexpr size_t PACC_OFF = VP_OFF + KSPLIT * PROJ_PART;    // per-chunk partial acc
constexpr size_t PACC_SZ = (size_t)NCHUNK * Bn * Hn * Tn * HDn; // 16*512*512
constexpr size_t PL_OFF = PACC_OFF + PACC_SZ;
constexpr size_t PL_SZ = (size_t)NCHUNK * Bn * Hn * Tn;
constexpr size_t AW_OFF = PL_OFF + PL_SZ;                   // merged attention out (B,T,C)
constexpr size_t AW_SZ = (size_t)Bn * Tn * Cn;
constexpr size_t OP_OFF = AW_OFF + AW_SZ;                   // final gemm partials
constexpr size_t OP_SZ = (size_t)KSPLIT * PROJ_PART;
constexpr size_t WS_FLOATS = OP_OFF + OP_SZ;                // ~34.9 MB

// ---------------- GEMM: Y_partial[sigma] = X(256xK-slice) @ W^T ----------------
// Block: 256 thr. Tile: 128 rows (i) x 64 cols (j). Per-thread 8x4 register tile.
// W^T tile staged transposed in LDS; X read via L1 broadcast loads.
__device__ __forceinline__ void gemm_body(const float* __restrict__ X,
                                          const float* __restrict__ W,
                                          float* __restrict__ Opart,
                                          int sigma, int jblk, int iblk) {
    __shared__ float wl[64][68]; // [k][j], pad 68
    const int tid = threadIdx.x;
    const int c = tid & 15, a = tid >> 4;
    const int j0 = jblk * 64;
    const int jj0 = j0 + c * 4;
    const int ib = iblk * 128 + a * 8;
    const int k0 = sigma * 256;

    float acc[8][4];
#pragma unroll
    for (int ii = 0; ii < 8; ++ii)
#pragma unroll
        for (int jj = 0; jj < 4; ++jj) acc[ii][jj] = 0.f;

    for (int kt = 0; kt < 4; ++kt) {
        const int k1 = k0 + kt * 64;
        // stage W[j0..j0+64)[k1..k1+64) transposed
#pragma unroll
        for (int stp = 0; stp < 4; ++stp) {
            int f4 = stp * 256 + tid;
            int jr = f4 >> 4, e4 = f4 & 15;
            float4 wv = *(const float4*)&W[(size_t)(j0 + jr) * Cn + k1 + e4 * 4];
            wl[e4 * 4 + 0][jr] = wv.x;
            wl[e4 * 4 + 1][jr] = wv.y;
            wl[e4 * 4 + 2][jr] = wv.z;
            wl[e4 * 4 + 3][jr] = wv.w;
        }
        __syncthreads();
#pragma unroll 2
        for (int k4 = 0; k4 < 16; ++k4) {
            float4 xv[8];
#pragma unroll
            for (int ii = 0; ii < 8; ++ii)
                xv[ii] = *(const float4*)&X[(size_t)(ib + ii) * Cn + k1 + k4 * 4];
#pragma unroll
            for (int kk = 0; kk < 4; ++kk) {
                float4 wv = *(const float4*)&wl[k4 * 4 + kk][c * 4];
#pragma unroll
                for (int ii = 0; ii < 8; ++ii) {
                    const float xs = (kk == 0) ? xv[ii].x : (kk == 1) ? xv[ii].y
                                   : (kk == 2) ? xv[ii].z : xv[ii].w;
                    acc[ii][0] += xs * wv.x;
                    acc[ii][1] += xs * wv.y;
                    acc[ii][2] += xs * wv.z;
                    acc[ii][3] += xs * wv.w;
                }
            }
        }
        __syncthreads();
    }
    float* op = Opart + (size_t)sigma * PROJ_PART;
#pragma unroll
    for (int ii = 0; ii < 8; ++ii) {
        float4 o = make_float4(acc[ii][0], acc[ii][1], acc[ii][2], acc[ii][3]);
        *(float4*)&op[(size_t)(ib + ii) * Cn + jj0] = o;
    }
}

__global__ __launch_bounds__(256) void proj3_kernel(
    const float* __restrict__ X, const float* __restrict__ W0,
    const float* __restrict__ W1, const float* __restrict__ W2,
    float* __restrict__ O0, float* __restrict__ O1, float* __restrict__ O2) {
    const int z = blockIdx.z;
    const float* W = (z < 4) ? W0 : (z < 8 ? W1 : W2);
    float* O = (z < 4) ? O0 : (z < 8 ? O1 : O2);
    gemm_body(X, W, O, z & 3, blockIdx.x, blockIdx.y);
}

__global__ __launch_bounds__(256) void gemm1_kernel(
    const float* __restrict__ X, const float* __restrict__ W, float* __restrict__ O) {
    gemm_body(X, W, O, blockIdx.z, blockIdx.x, blockIdx.y);
}

// ---------------- Attention partials ----------------
// Grid (cq=16, h=16, b=32), block 256 = 4 independent waves, each owns 64 key rows.
__global__ __launch_bounds__(256) void attn_kernel(
    const float* __restrict__ qpart, const float* __restrict__ kpart,
    const float* __restrict__ vpart, const float* __restrict__ ck,
    const float* __restrict__ cv, const int* __restrict__ clen,
    float* __restrict__ pacc, float* __restrict__ pl) {
    const int cq = blockIdx.x, h = blockIdx.y, b = blockIdx.z;
    const int cl = clen[b];
    if (!(cq == 0 || cq * 256 < cl)) return; // inactive chunk (uniform)

    const int tid = threadIdx.x, wave = tid >> 6, lane = tid & 63;

    __shared__ float q_l[Tn][HDn];       // 2 KB (shared, duplicate-written)
    __shared__ float k_l[4][64][36];     // 36 KB (per-wave, e-halved, pad 36)
    __shared__ float p_l[4][64][12];     // 12 KB (per-wave, pad 12)

    // stage q = sum of 4 K-split partials; every wave writes identical values
#pragma unroll
    for (int stp = 0; stp < 2; ++stp) {
        int f4 = stp * 64 + lane;
        int t = f4 >> 4, e4 = f4 & 15;
        const float* src = qpart + (size_t)(b * Tn + t) * Cn + h * HDn + e4 * 4;
        float4 a0 = *(const float4*)(src);
        float4 a1 = *(const float4*)(src + PROJ_PART);
        float4 a2 = *(const float4*)(src + 2 * PROJ_PART);
        float4 a3 = *(const float4*)(src + 3 * PROJ_PART);
        float4 q4 = make_float4(a0.x + a1.x + a2.x + a3.x, a0.y + a1.y + a2.y + a3.y,
                                a0.z + a1.z + a2.z + a3.z, a0.w + a1.w + a2.w + a3.w);
        *(float4*)&q_l[t][e4 * 4] = q4;
    }

    const int r0 = cq * 256 + wave * 64;
    int n_valid = cl - r0;
    n_valid = n_valid < 0 ? 0 : (n_valid > 64 ? 64 : n_valid);
    const bool newwave = (cq == 0 && wave == 0);

    float l_lane[8], accv[8];
#pragma unroll
    for (int t = 0; t < 8; ++t) { l_lane[t] = 0.f; accv[t] = 0.f; }

    if (n_valid > 0) {
        float sc[8];
#pragma unroll
        for (int t = 0; t < 8; ++t) sc[t] = 0.f;
#pragma unroll
        for (int sg = 0; sg < 2; ++sg) {
            // stage K half-tile (64 rows x 32 e), coalesced 128B segments
#pragma unroll
            for (int i = 0; i < 8; ++i) {
                int idx = i * 64 + lane;
                int row = idx >> 3, e4 = idx & 7;
                float4 kv = *(const float4*)&ck[((size_t)b * Sn + r0 + row) * Cn + h * HDn + sg * 32 + e4 * 4];
                *(float4*)&k_l[wave][row][e4 * 4] = kv;
            }
            // in-wave RAW on LDS: compiler inserts lgkmcnt waits
#pragma unroll
            for (int e4 = 0; e4 < 8; ++e4) {
                float4 kv = *(const float4*)&k_l[wave][lane][e4 * 4];
#pragma unroll
                for (int t = 0; t < 8; ++t) {
                    float4 qv = *(const float4*)&q_l[t][sg * 32 + e4 * 4];
                    sc[t] += kv.x * qv.x + kv.y * qv.y + kv.z * qv.z + kv.w * qv.w;
                }
            }
        }
        const bool val = lane < n_valid;
        float p[8];
#pragma unroll
        for (int t = 0; t < 8; ++t) {
            p[t] = val ? __expf(sc[t] * SCALE) : 0.f;
            l_lane[t] += p[t];
        }
        *(float4*)&p_l[wave][lane][0] = make_float4(p[0], p[1], p[2], p[3]);
        *(float4*)&p_l[wave][lane][4] = make_float4(p[4], p[5], p[6], p[7]);
        // PV: V straight from global, coalesced 256B per row
        const float* vbase = cv + ((size_t)b * Sn + r0) * Cn + h * HDn + lane;
        int s = 0;
        for (; s + 4 <= n_valid; s += 4) {
            float v0 = vbase[(size_t)(s + 0) * Cn];
            float v1 = vbase[(size_t)(s + 1) * Cn];
            float v2 = vbase[(size_t)(s + 2) * Cn];
            float v3 = vbase[(size_t)(s + 3) * Cn];
#pragma unroll
            for (int u = 0; u < 4; ++u) {
                float v = (u == 0) ? v0 : (u == 1) ? v1 : (u == 2) ? v2 : v3;
                float4 qa = *(const float4*)&p_l[wave][s + u][0];
                float4 qb = *(const float4*)&p_l[wave][s + u][4];
                accv[0] += qa.x * v; accv[1] += qa.y * v; accv[2] += qa.z * v; accv[3] += qa.w * v;
                accv[4] += qb.x * v; accv[5] += qb.y * v; accv[6] += qb.z * v; accv[7] += qb.w * v;
            }
        }
        for (; s < n_valid; ++s) {
            float v = vbase[(size_t)s * Cn];
            float4 qa = *(const float4*)&p_l[wave][s][0];
            float4 qb = *(const float4*)&p_l[wave][s][4];
            accv[0] += qa.x * v; accv[1] += qa.y * v; accv[2] += qa.z * v; accv[3] += qa.w * v;
            accv[4] += qb.x * v; accv[5] += qb.y * v; accv[6] += qb.z * v; accv[7] += qb.w * v;
        }
    }

    if (newwave) {
        // max(cache_len) for the zero-pad denominator term
        int mv = clen[lane & 31];
#pragma unroll
        for (int off = 16; off >= 1; off >>= 1) {
            int o = __shfl_xor(mv, off);
            mv = mv > o ? mv : o;
        }
        const int pad = mv - cl;
        float sc[8];
#pragma unroll
        for (int t = 0; t < 8; ++t) sc[t] = 0.f;
#pragma unroll
        for (int sg = 0; sg < 2; ++sg) {
            { // stage 8 new-key rows (sum 4 partials)
                int row = lane >> 3, e4 = lane & 7;
                const float* src = kpart + (size_t)(b * Tn + row) * Cn + h * HDn + sg * 32 + e4 * 4;
                float4 a0 = *(const float4*)(src);
                float4 a1 = *(const float4*)(src + PROJ_PART);
                float4 a2 = *(const float4*)(src + 2 * PROJ_PART);
                float4 a3 = *(const float4*)(src + 3 * PROJ_PART);
                float4 kv = make_float4(a0.x + a1.x + a2.x + a3.x, a0.y + a1.y + a2.y + a3.y,
                                        a0.z + a1.z + a2.z + a3.z, a0.w + a1.w + a2.w + a3.w);
                *(float4*)&k_l[0][row][e4 * 4] = kv;
            }
#pragma unroll
            for (int e4 = 0; e4 < 8; ++e4) {
                float4 kv = *(const float4*)&k_l[0][lane][e4 * 4];
#pragma unroll
                for (int t = 0; t < 8; ++t) {
                    float4 qv = *(const float4*)&q_l[t][sg * 32 + e4 * 4];
                    sc[t] += kv.x * qv.x + kv.y * qv.y + kv.z * qv.z + kv.w * qv.w;
                }
            }
        }
        const bool val = lane < Tn;
        float p[8];
#pragma unroll
        for (int t = 0; t < 8; ++t) {
            p[t] = val ? __expf(sc[t] * SCALE) : 0.f;
            l_lane[t] += p[t];
        }
        if (lane == 0) {
#pragma unroll
            for (int t = 0; t < 8; ++t) l_lane[t] += (float)pad;
        }
        *(float4*)&p_l[0][lane][0] = make_float4(p[0], p[1], p[2], p[3]);
        *(float4*)&p_l[0][lane][4] = make_float4(p[4], p[5], p[6], p[7]);
#pragma unroll
        for (int s = 0; s < Tn; ++s) {
            const float* vs = vpart + (size_t)(b * Tn + s) * Cn + h * HDn + lane;
            float v = vs[0] + vs[PROJ_PART] + vs[2 * PROJ_PART] + vs[3 * PROJ_PART];
            float4 qa = *(const float4*)&p_l[0][s][0];
            float4 qb = *(const float4*)&p_l[0][s][4];
            accv[0] += qa.x * v; accv[1] += qa.y * v; accv[2] += qa.z * v; accv[3] += qa.w * v;
            accv[4] += qb.x * v; accv[5] += qb.y * v; accv[6] += qb.z * v; accv[7] += qb.w * v;
        }
    }

    // reduce l over lanes (per wave)
    float lr[8];
#pragma unroll
    for (int t = 0; t < 8; ++t) {
        float v = l_lane[t];
#pragma unroll
        for (int off = 32; off >= 1; off >>= 1) v += __shfl_xor(v, off);
        lr[t] = v;
    }

    // block reduce across 4 waves via LDS (reuse k_l)
    __syncthreads();
    float* redacc = &k_l[0][0][0]; // 2048 floats
    float* redl = redacc + 2048;   // 32 floats
#pragma unroll
    for (int t = 0; t < 8; ++t) redacc[(wave * 8 + t) * 64 + lane] = accv[t];
    if (lane == 0) {
#pragma unroll
        for (int t = 0; t < 8; ++t) redl[wave * 8 + t] = lr[t];
    }
    __syncthreads();
    const size_t obase = (size_t)((cq * Bn + b) * Hn + h);
#pragma unroll
    for (int rep = 0; rep < 2; ++rep) {
        int e = rep * 256 + tid;
        int t = e >> 6, d = e & 63;
        float s = redacc[t * 64 + d] + redacc[(8 + t) * 64 + d] +
                  redacc[(16 + t) * 64 + d] + redacc[(24 + t) * 64 + d];
        pacc[obase * 512 + e] = s;
    }
    if (tid < 8) pl[obase * 8 + tid] = redl[tid] + redl[8 + tid] + redl[16 + tid] + redl[24 + tid];
}

// ---------------- Merge chunk partials, normalize ----------------
__global__ __launch_bounds__(64) void attn_merge_kernel(
    const float* __restrict__ pacc, const float* __restrict__ pl,
    const int* __restrict__ clen, float* __restrict__ aw) {
    const int h = blockIdx.x, b = blockIdx.y, lane = threadIdx.x;
    const int cl = clen[b];
    int nch = (cl + 255) >> 8;
    if (nch < 1) nch = 1;
    float acc[8], l[8];
#pragma unroll
    for (int t = 0; t < 8; ++t) { acc[t] = 0.f; l[t] = 0.f; }
    for (int c = 0; c < nch; ++c) {
        const size_t base = (size_t)((c * Bn + b) * Hn + h);
#pragma unroll
        for (int t = 0; t < 8; ++t) acc[t] += pacc[base * 512 + t * 64 + lane];
#pragma unroll
        for (int t = 0; t < 8; ++t) l[t] += pl[base * 8 + t];
    }
#pragma unroll
    for (int t = 0; t < 8; ++t)
        aw[(size_t)(b * Tn + t) * Cn + h * HDn + lane] = acc[t] / l[t];
}

// ---------------- Sum final-GEMM partials + bias ----------------
__global__ __launch_bounds__(256) void bias_out_kernel(
    const float* __restrict__ opart, const float* __restrict__ bo, float* __restrict__ out) {
    const int f4 = blockIdx.x * 256 + threadIdx.x; // 65536 float4s
    const int col4 = f4 & 255;
    const float* p = opart + (size_t)f4 * 4;
    float4 a0 = *(const float4*)(p);
    float4 a1 = *(const float4*)(p + PROJ_PART * 4 / 4 * 1); // PROJ_PART floats
    float4 a2 = *(const float4*)(p + PROJ_PART * 2);
    float4 a3 = *(const float4*)(p + PROJ_PART * 3);
    // fix a1 expression clarity:
    a1 = *(const float4*)(p + PROJ_PART);
    float4 bv = *(const float4*)&bo[col4 * 4];
    float4 o = make_float4(a0.x + a1.x + a2.x + a3.x + bv.x,
                           a0.y + a1.y + a2.y + a3.y + bv.y,
                           a0.z + a1.z + a2.z + a3.z + bv.z,
                           a0.w + a1.w + a2.w + a3.w + bv.w);
    *(float4*)&out[(size_t)f4 * 4] = o;
}

extern "C" void kernel_launch(void* const* d_in, const int* in_sizes, int n_in,
                              void* d_out, int out_size, void* d_ws, size_t ws_size,
                              hipStream_t stream) {
    const float* x  = (const float*)d_in[0];
    const float* ck = (const float*)d_in[1];
    const float* cv = (const float*)d_in[2];
    const int*   cl = (const int*)d_in[3];
    const float* wq = (const float*)d_in[4];
    const float* wk = (const float*)d_in[5];
    const float* wv = (const float*)d_in[6];
    const float* wo = (const float*)d_in[7];
    const float* bo = (const float*)d_in[8];
    float* out = (float*)d_out;
    float* ws = (float*)d_ws;

    float* qpart = ws + QP_OFF;
    float* kpart = ws + KP_OFF;
    float* vpart = ws + VP_OFF;
    float* pacc  = ws + PACC_OFF;
    float* pl    = ws + PL_OFF;
    float* aw    = ws + AW_OFF;
    float* opart = ws + OP_OFF;

    // 1) q/k/v projections (K-split-4 partials)
    proj3_kernel<<<dim3(16, 2, 12), dim3(256), 0, stream>>>(x, wq, wk, wv, qpart, kpart, vpart);
    // 2) attention partials per (chunk, head, batch)
    attn_kernel<<<dim3(NCHUNK, Hn, Bn), dim3(256), 0, stream>>>(qpart, kpart, vpart, ck, cv, cl, pacc, pl);
    // 3) merge + normalize
    attn_merge_kernel<<<dim3(Hn, Bn), dim3(64), 0, stream>>>(pacc, pl, cl, aw);
    // 4) output projection (K-split-4 partials)
    gemm1_kernel<<<dim3(16, 2, KSPLIT), dim3(256), 0, stream>>>(aw, wo, opart);
    // 5) sum partials + bias
    bias_out_kernel<<<dim3(256), dim3(256), 0, stream>>>(opart, bo, out);
}